// Round 1
// baseline (57.003 us; speedup 1.0000x reference)
//
#include <hip/hip_runtime.h>
#include <hip/hip_bf16.h>
#include <cstdint>

// LearnableUpsamplingLayer: polyphase decomposition + bf16 MFMA.
// B=8, T=16384, C=64, F=64, filter=5, leaky 0.3.
// out[b, 2t+0, f] = sum_c E0[c,f] x[t-1,c] + E1[c,f] x[t,c] + E2[c,f] x[t+1,c]
// out[b, 2t+1, f] = sum_c O0[c,f] x[t-1,c] + O1[c,f] x[t,c] + O2[c,f] x[t+1,c] + O3[c,f] x[t+2,c]
// (x out of [0,T) treated as zero). Exception: frames 0,1 (t=0) must NOT include
// the blend[-1] leakage term -> fixed up exactly in-kernel.

#define B_ 8
#define T_ 16384
#define TWO_T 32768
#define TM 64              // time-pairs per block
#define NFR (TM + 3)       // staged frames: t0-1 .. t0+TM+1
#define LDS_STRIDE 72      // ushorts per frame row (padded: 144B = 36 words -> 2-way only)

typedef __bf16 bf16x8 __attribute__((ext_vector_type(8)));
typedef float  f32x4  __attribute__((ext_vector_type(4)));
typedef unsigned short u16x8 __attribute__((ext_vector_type(8)));
typedef unsigned short u16x4 __attribute__((ext_vector_type(4)));

__device__ __forceinline__ unsigned short f2bf(float f) {
    union { float f; uint32_t u; } v; v.f = f;
    uint32_t u = v.u;
    return (unsigned short)((u + 0x7FFFu + ((u >> 16) & 1u)) >> 16);
}

__device__ __forceinline__ float sigmoidf_(float z) {
    return 1.0f / (1.0f + expf(-z));
}

// ---------------- prep: build the 7 polyphase matrices as packed bf16 MFMA
// B-fragments in d_ws. Fragment (phase, ks, nt): lane l, elem i holds
// M[tap = ks>>1][c = (ks&1)*32 + (l>>4)*8 + i][n = nt*16 + (l&15)].
// even frags at fi = ks*4+nt (ks<6), odd at fi = 24 + ks*4+nt (ks<8).
__global__ void lu_prep_kernel(const float* __restrict__ iw,
                               const float* __restrict__ ck,
                               unsigned short* __restrict__ bp) {
    int fi = blockIdx.x;          // 0..55
    int l  = threadIdx.x;         // 0..63
    int phase, ks, nt;
    if (fi < 24) { phase = 0; ks = fi >> 2; nt = fi & 3; }
    else         { phase = 1; ks = (fi - 24) >> 2; nt = (fi - 24) & 3; }
    int tap = ks >> 1;
    int n   = nt * 16 + (l & 15);
    int c0  = ((ks & 1) << 5) + ((l >> 4) << 3);
    u16x8 pk;
#pragma unroll
    for (int i = 0; i < 8; ++i) {
        int c = c0 + i;
        float w = sigmoidf_(iw[c]);
        float v;
        #define CK(k) ck[((k) * 64 + c) * 64 + n]
        if (phase == 0) {
            if (tap == 0)      v = CK(0) + w * CK(1);
            else if (tap == 1) v = (1.f - w) * CK(1) + CK(2) + w * CK(3);
            else               v = (1.f - w) * CK(3) + CK(4);
        } else {
            if (tap == 0)      v = w * CK(0);
            else if (tap == 1) v = (1.f - w) * CK(0) + CK(1) + w * CK(2);
            else if (tap == 2) v = (1.f - w) * CK(2) + CK(3) + w * CK(4);
            else               v = (1.f - w) * CK(4);
        }
        #undef CK
        pk[i] = f2bf(v);
    }
    *(u16x8*)(bp + (((size_t)fi * 64) + l) * 8) = pk;
}

// ---------------- main kernel ----------------
__global__ __launch_bounds__(256) void lu_main_kernel(
        const float* __restrict__ x,
        const unsigned short* __restrict__ bp,
        const float* __restrict__ bias,
        const float* __restrict__ iw,
        const float* __restrict__ ck,
        float* __restrict__ out) {
    __shared__ __align__(16) unsigned short xl[NFR * LDS_STRIDE];

    int bid   = blockIdx.x;
    int b     = bid >> 8;       // 256 chunks per batch
    int chunk = bid & 255;
    int t0    = chunk * TM;
    int tid   = threadIdx.x;
    int lane  = tid & 63;
    int wv    = tid >> 6;       // wave id = n-tile (16 filters each)

    // ---- stage x[t0-1 .. t0+TM+1] as bf16 into LDS (zero outside [0,T)) ----
#pragma unroll
    for (int it = 0; it < 5; ++it) {
        int idx = it * 256 + tid;
        if (idx < NFR * 16) {
            int j  = idx >> 4;
            int c4 = (idx & 15) << 2;
            int gf = t0 - 1 + j;
            float4 val = make_float4(0.f, 0.f, 0.f, 0.f);
            if (gf >= 0 && gf < T_)
                val = *(const float4*)(x + ((size_t)b * T_ + gf) * 64 + c4);
            u16x4 pk;
            pk[0] = f2bf(val.x); pk[1] = f2bf(val.y);
            pk[2] = f2bf(val.z); pk[3] = f2bf(val.w);
            *(u16x4*)(xl + j * LDS_STRIDE + c4) = pk;
        }
    }

    // ---- load this wave's 14 B-fragments into registers ----
    bf16x8 Be[6], Bo[8];
#pragma unroll
    for (int ks = 0; ks < 6; ++ks)
        Be[ks] = __builtin_bit_cast(bf16x8,
            *(const u16x8*)(bp + (((size_t)(ks * 4 + wv)) * 64 + lane) * 8));
#pragma unroll
    for (int ks = 0; ks < 8; ++ks)
        Bo[ks] = __builtin_bit_cast(bf16x8,
            *(const u16x8*)(bp + (((size_t)(24 + ks * 4 + wv)) * 64 + lane) * 8));

    float bias_f = bias[(wv << 4) + (lane & 15)];

    __syncthreads();

    const int arow = lane & 15;         // A-operand row within 16-row tile
    const int ac0  = (lane >> 4) << 3;  // A-operand k sub-offset
    const size_t out_base = (size_t)b * TWO_T * 64 + (wv << 4) + (lane & 15);

#pragma unroll
    for (int rt = 0; rt < 4; ++rt) {
        // even phase: 3 taps (K=192)
        f32x4 acc = {0.f, 0.f, 0.f, 0.f};
#pragma unroll
        for (int ks = 0; ks < 6; ++ks) {
            int tap = ks >> 1;
            int c0  = ((ks & 1) << 5) + ac0;
            int row = (rt << 4) + arow + tap;
            bf16x8 a = __builtin_bit_cast(bf16x8,
                *(const u16x8*)(xl + row * LDS_STRIDE + c0));
            acc = __builtin_amdgcn_mfma_f32_16x16x32_bf16(a, Be[ks], acc, 0, 0, 0);
        }
#pragma unroll
        for (int i = 0; i < 4; ++i) {
            int tl = (rt << 4) + ((lane >> 4) << 2) + i;
            float v = acc[i] + bias_f;
            v = v >= 0.f ? v : 0.3f * v;
            out[out_base + (size_t)((t0 + tl) << 1) * 64] = v;
        }
        // odd phase: 4 taps (K=256)
        f32x4 acco = {0.f, 0.f, 0.f, 0.f};
#pragma unroll
        for (int ks = 0; ks < 8; ++ks) {
            int tap = ks >> 1;
            int c0  = ((ks & 1) << 5) + ac0;
            int row = (rt << 4) + arow + tap;
            bf16x8 a = __builtin_bit_cast(bf16x8,
                *(const u16x8*)(xl + row * LDS_STRIDE + c0));
            acco = __builtin_amdgcn_mfma_f32_16x16x32_bf16(a, Bo[ks], acco, 0, 0, 0);
        }
#pragma unroll
        for (int i = 0; i < 4; ++i) {
            int tl = (rt << 4) + ((lane >> 4) << 2) + i;
            float v = acco[i] + bias_f;
            v = v >= 0.f ? v : 0.3f * v;
            out[out_base + (size_t)(((t0 + tl) << 1) + 1) * 64] = v;
        }
    }

    // ---- exact fixup of output frames 0,1 (blend[-1] leakage) ----
    if (chunk == 0) {
        __syncthreads();
        if (tid < 128) {
            int p = tid >> 6;      // 0: frame 0 (even t=0), 1: frame 1 (odd t=0)
            int f = tid & 63;
            float acc = 0.f;
            for (int c = 0; c < 64; ++c) {
                float x0 = x[(size_t)b * T_ * 64 + 0 * 64 + c];
                float x1 = x[(size_t)b * T_ * 64 + 1 * 64 + c];
                float w  = sigmoidf_(iw[c]);
                float bl0 = w * x0 + (1.f - w) * x1;
                if (p == 0) {
                    acc += ck[(2 * 64 + c) * 64 + f] * x0
                         + ck[(3 * 64 + c) * 64 + f] * bl0
                         + ck[(4 * 64 + c) * 64 + f] * x1;
                } else {
                    float x2 = x[(size_t)b * T_ * 64 + 2 * 64 + c];
                    float bl1 = w * x1 + (1.f - w) * x2;
                    acc += ck[(1 * 64 + c) * 64 + f] * x0
                         + ck[(2 * 64 + c) * 64 + f] * bl0
                         + ck[(3 * 64 + c) * 64 + f] * x1
                         + ck[(4 * 64 + c) * 64 + f] * bl1;
                }
            }
            acc += bias[f];
            acc = acc >= 0.f ? acc : 0.3f * acc;
            out[(size_t)b * TWO_T * 64 + (size_t)p * 64 + f] = acc;
        }
    }
}

extern "C" void kernel_launch(void* const* d_in, const int* in_sizes, int n_in,
                              void* d_out, int out_size, void* d_ws, size_t ws_size,
                              hipStream_t stream) {
    (void)in_sizes; (void)n_in; (void)out_size; (void)ws_size;
    const float* x    = (const float*)d_in[0];
    const float* iw   = (const float*)d_in[1];
    const float* ck   = (const float*)d_in[2];
    const float* bias = (const float*)d_in[3];
    float* out = (float*)d_out;
    unsigned short* bp = (unsigned short*)d_ws;   // needs 57,344 B

    lu_prep_kernel<<<56, 64, 0, stream>>>(iw, ck, bp);
    lu_main_kernel<<<2048, 256, 0, stream>>>(x, bp, bias, iw, ck, out);
}